// Round 9
// baseline (2711.170 us; speedup 1.0000x reference)
//
#include <hip/hip_runtime.h>
#include <math.h>

#define SEQ 2048
#define BATCH 64
#define INF 256
#define HID 256
#define NL 2

typedef __attribute__((ext_vector_type(2))) _Float16 half2_t;

// ---------------------------------------------------------------------------
// Phase A: pre[l][m][h] = sum_i x[m][i] * W[l][h][i] + bias[l][h]
// (unchanged — ~600 us; attack once rnn hits its floor)
// ---------------------------------------------------------------------------
__global__ __launch_bounds__(256) void xw_kernel(
    const float* __restrict__ x,
    const float* __restrict__ W,
    const float* __restrict__ bias,
    float* __restrict__ pre0,
    float* __restrict__ pre1)
{
    __shared__ float As[64][68];
    __shared__ float Bs[64][68];

    const int mb = blockIdx.x * 64;
    const int nb = blockIdx.y * 64;
    const int l  = nb >> 8;
    const int hb = nb & 255;

    const int tid = threadIdx.x;
    const int tx = tid & 15;
    const int ty = tid >> 4;

    const float* Wl = W + (size_t)l * HID * INF;

    float acc[4][4] = {};

    const int lrow = tid >> 4;
    const int lkq  = tid & 15;

    for (int kb = 0; kb < INF; kb += 64) {
        #pragma unroll
        for (int rr = 0; rr < 4; ++rr) {
            const int m = lrow + rr * 16;
            float4 va = *(const float4*)&x[(size_t)(mb + m) * INF + kb + lkq * 4];
            As[lkq*4 + 0][m] = va.x; As[lkq*4 + 1][m] = va.y;
            As[lkq*4 + 2][m] = va.z; As[lkq*4 + 3][m] = va.w;
            float4 vb = *(const float4*)&Wl[(size_t)(hb + m) * INF + kb + lkq * 4];
            Bs[lkq*4 + 0][m] = vb.x; Bs[lkq*4 + 1][m] = vb.y;
            Bs[lkq*4 + 2][m] = vb.z; Bs[lkq*4 + 3][m] = vb.w;
        }
        __syncthreads();

        #pragma unroll 8
        for (int k = 0; k < 64; ++k) {
            float4 a = *(const float4*)&As[k][ty * 4];
            float4 b = *(const float4*)&Bs[k][tx * 4];
            acc[0][0] = fmaf(a.x, b.x, acc[0][0]);
            acc[0][1] = fmaf(a.x, b.y, acc[0][1]);
            acc[0][2] = fmaf(a.x, b.z, acc[0][2]);
            acc[0][3] = fmaf(a.x, b.w, acc[0][3]);
            acc[1][0] = fmaf(a.y, b.x, acc[1][0]);
            acc[1][1] = fmaf(a.y, b.y, acc[1][1]);
            acc[1][2] = fmaf(a.y, b.z, acc[1][2]);
            acc[1][3] = fmaf(a.y, b.w, acc[1][3]);
            acc[2][0] = fmaf(a.z, b.x, acc[2][0]);
            acc[2][1] = fmaf(a.z, b.y, acc[2][1]);
            acc[2][2] = fmaf(a.z, b.z, acc[2][2]);
            acc[2][3] = fmaf(a.z, b.w, acc[2][3]);
            acc[3][0] = fmaf(a.w, b.x, acc[3][0]);
            acc[3][1] = fmaf(a.w, b.y, acc[3][1]);
            acc[3][2] = fmaf(a.w, b.z, acc[3][2]);
            acc[3][3] = fmaf(a.w, b.w, acc[3][3]);
        }
        __syncthreads();
    }

    float bv[4];
    #pragma unroll
    for (int j = 0; j < 4; ++j)
        bv[j] = bias[l * HID + hb + tx * 4 + j];

    float* dst = (l == 0) ? pre0 : pre1;
    #pragma unroll
    for (int i = 0; i < 4; ++i) {
        float4 o;
        o.x = acc[i][0] + bv[0];
        o.y = acc[i][1] + bv[1];
        o.z = acc[i][2] + bv[2];
        o.w = acc[i][3] + bv[3];
        *(float4*)&dst[(size_t)(mb + ty * 4 + i) * HID + hb + tx * 4] = o;
    }
}

// fast tanh: clamp + hw exp. |err| ~1e-6 rel.
__device__ __forceinline__ float tanh_fast(float x) {
    float xc = fminf(fmaxf(x, -12.0f), 12.0f);
    float e  = __expf(2.0f * xc);
    return __fdividef(e - 1.0f, e + 1.0f);
}

// packed f16 dot2 with fp32 accumulate (v_dot2_f32_f16); fallback = 2 fma
__device__ __forceinline__ float dot2(unsigned ua, unsigned ub, float c) {
#if __has_builtin(__builtin_amdgcn_fdot2)
    return __builtin_amdgcn_fdot2(__builtin_bit_cast(half2_t, ua),
                                  __builtin_bit_cast(half2_t, ub), c, false);
#else
    half2_t a = __builtin_bit_cast(half2_t, ua);
    half2_t b = __builtin_bit_cast(half2_t, ub);
    c = fmaf((float)a.x, (float)b.x, c);
    return fmaf((float)a.y, (float)b.y, c);
#endif
}

__device__ __forceinline__ unsigned pk16(float a, float b) {
#if __has_builtin(__builtin_amdgcn_cvt_pkrtz)
    return __builtin_bit_cast(unsigned, __builtin_amdgcn_cvt_pkrtz(a, b));
#else
    half2_t h; h.x = (_Float16)a; h.y = (_Float16)b;
    return __builtin_bit_cast(unsigned, h);
#endif
}

#define U_LDS_BYTES (128 * 1024)

// ---------------------------------------------------------------------------
// Phase B v6: U lives in 128 KB dynamic LDS as packed f16 (allocator-proof:
// rounds 3/4/6/7 proved per-thread register-resident U is unobtainable).
// 128 blocks x 512 threads, 1 block/CU (LDS-limited).
//   g = tid>>1 (output row), c = tid&1 (k-half of 128 terms).
// Thread slice = row g half c = 16 uint4 at Ulds[tid*16 + slot].
// SLOT XOR-SWIZZLE (slot = r ^ (tid&7)): for uniform r the 64 lanes spread
// over all 8 bank groups -> conflict-free; unswizzled would be 16-way.
// h ping-pong: [2][2][68] uints — 68-pad puts the c=0/c=1 broadcast
// addresses on distinct bank groups (fixes round 7's 1.34e8 conflicts).
// Per step/thread: 16 swizzled U b128 reads + 16 broadcast h b128 reads +
// 64 fdot2 (fp32 accum) -> shfl reduce -> tanh -> pack -> 1 barrier.
// Step floor: 128KB LDS re-read @ ~128-256B/cyc = 512-1024 cyc.
// ---------------------------------------------------------------------------
__global__ __launch_bounds__(512, 2) void rnn_kernel(
    const float* __restrict__ h0,
    const float* __restrict__ U,
    const float* pre0,
    const float* pre1,
    float* out,
    float* hn)
{
    extern __shared__ uint4 Ulds[];              // 512 slices x 16 uint4 = 128 KB
    __shared__ unsigned h16[2][2][68];           // [buf][k-half][64 pairs + 4 pad]

    const int l = blockIdx.x >> 6;
    const int b = blockIdx.x & 63;
    const int tid = threadIdx.x;
    const int g = tid >> 1;          // 0..255
    const int c = tid & 1;           // 0..1
    const int s7 = tid & 7;          // swizzle key

    // One-time stage: pack U[l][g][c*128..+128) into own LDS slice, swizzled.
    const float* Urow = U + (size_t)l * HID * HID + (size_t)g * HID + c * 128;
    uint4* myU = Ulds + tid * 16;
    #pragma unroll
    for (int r = 0; r < 16; ++r) {
        float4 f0 = *(const float4*)&Urow[r * 8];
        float4 f1 = *(const float4*)&Urow[r * 8 + 4];
        uint4 p;
        p.x = pk16(f0.x, f0.y);
        p.y = pk16(f0.z, f0.w);
        p.z = pk16(f1.x, f1.y);
        p.w = pk16(f1.z, f1.w);
        myU[r ^ s7] = p;             // content chunk r stored at slot r^s7
    }

    if (tid < 128) {                 // h0 -> packed pairs, buffer 0
        const float* h0p = h0 + (size_t)l * BATCH * HID + (size_t)b * HID;
        h16[0][tid >> 6][tid & 63] = pk16(h0p[tid * 2], h0p[tid * 2 + 1]);
    }
    __syncthreads();

    const float* pre = (l == 0) ? pre0 : pre1;
    const size_t bh = (size_t)b * HID + g;

    float preCur = pre[bh];          // t = 0
    float v = 0.0f;
    int cur = 0;

    for (int t = 0; t < SEQ; ++t) {
        float preNext = (t + 1 < SEQ) ? pre[(size_t)(t + 1) * BATCH * HID + bh] : 0.0f;

        float a0 = 0.f, a1 = 0.f, a2 = 0.f, a3 = 0.f;
        const uint4* hc = (const uint4*)&h16[cur][c][0];
        #pragma unroll
        for (int r = 0; r < 16; ++r) {
            uint4 w  = hc[r];            // broadcast (2 addrs, distinct banks)
            uint4 uu = myU[r ^ s7];      // swizzled -> 8 bank groups covered
            a0 = dot2(w.x, uu.x, a0);
            a1 = dot2(w.y, uu.y, a1);
            a2 = dot2(w.z, uu.z, a2);
            a3 = dot2(w.w, uu.w, a3);
        }
        float s = (a0 + a1) + (a2 + a3);
        s += __shfl_xor(s, 1);       // combine the two k-halves (tid^1)

        v = tanh_fast(s + preCur);

        float vp = __shfl_xor(v, 2); // partner row g^1's value (same c)
        if (c == 0) {
            if ((g & 1) == 0)
                h16[cur ^ 1][g >> 7][(g >> 1) & 63] = pk16(v, vp);
            if (l == 1)
                out[(size_t)t * BATCH * HID + bh] = v;
        }
        preCur = preNext;
        cur ^= 1;
        __syncthreads();
    }

    if (c == 0)
        hn[(size_t)l * BATCH * HID + bh] = v;
}

extern "C" void kernel_launch(void* const* d_in, const int* in_sizes, int n_in,
                              void* d_out, int out_size, void* d_ws, size_t ws_size,
                              hipStream_t stream) {
    const float* x  = (const float*)d_in[0];   // [SEQ][B][IN]
    const float* h0 = (const float*)d_in[1];   // [L][B][H]
    const float* W  = (const float*)d_in[2];   // [L][H][IN]
    const float* U  = (const float*)d_in[3];   // [L][H][H]
    const float* bs = (const float*)d_in[4];   // [L][H]

    float* out  = (float*)d_out;               // [SEQ][B][H] then [L][B][H]
    float* pre0 = (float*)d_ws;                // l=0 preacts (134 MB)
    float* pre1 = out;                         // l=1 preacts staged in-place
    float* hn   = out + (size_t)SEQ * BATCH * HID;

    // allow 128 KB dynamic LDS (default cap is 64 KB); idempotent, capture-safe
    static bool attr_done = false;             // host-side only, not work-skipping
    if (!attr_done) {
        hipFuncSetAttribute((const void*)rnn_kernel,
                            hipFuncAttributeMaxDynamicSharedMemorySize,
                            U_LDS_BYTES);
        attr_done = true;
    }

    dim3 gridA(SEQ * BATCH / 64, (NL * HID) / 64);
    xw_kernel<<<gridA, 256, 0, stream>>>(x, W, bs, pre0, pre1);

    rnn_kernel<<<NL * BATCH, 512, U_LDS_BYTES, stream>>>(h0, U, pre0, pre1, out, hn);
}